// Round 3
// baseline (503.057 us; speedup 1.0000x reference)
//
#include <hip/hip_runtime.h>

// LSTM via MFMA, round 3: B=8192, T=512, IN=5, H=32.
// Block = 512 thr = 8 waves, group = 16 batches. Wave w: jh=w&1 (j half),
// rq=w>>1 (acc row quarter) -> 1 cell/lane. 12 MFMAs/wave/step (redundant across
// rq but matrix pipe has headroom); occupancy 4 waves/SIMD.
// x pre-packed to bf16 hi/lo u32 by a prepass kernel (d_ws); raw s_barrier with
// lgkmcnt-only drain so x prefetch spans the barrier.

typedef __attribute__((ext_vector_type(8))) short short8;
typedef __attribute__((ext_vector_type(4))) float f32x4;
typedef __attribute__((ext_vector_type(4))) unsigned int u32x4;

static constexpr int BB  = 8192;
static constexpr int TT  = 512;
static constexpr int NIN = 5;
static constexpr int HH  = 32;

__device__ __forceinline__ unsigned short bf_rne(float f) {
    unsigned int u = __float_as_uint(f);
    u = (u + 0x7FFFu + ((u >> 16) & 1u)) >> 16;
    return (unsigned short)u;
}
__device__ __forceinline__ float bf_f32(unsigned short h) {
    return __uint_as_float((unsigned int)h << 16);
}
__device__ __forceinline__ float fast_sigmoid(float x) {
    float e = __builtin_amdgcn_exp2f(-1.4426950408889634f * x);
    return __builtin_amdgcn_rcpf(1.0f + e);
}
__device__ __forceinline__ float fast_tanh(float x) {
    float e = __builtin_amdgcn_exp2f(2.8853900817779268f * x);
    return 1.0f - 2.0f * __builtin_amdgcn_rcpf(1.0f + e);
}

// ---- prepass: pack x[b,t,0..4] f32 -> u32 (lo16 = bf16 hi part, hi16 = bf16 lo part)
__global__ __launch_bounds__(256) void pack_x(const float* __restrict__ x,
                                              unsigned int* __restrict__ xp) {
    int idx = blockIdx.x * 256 + threadIdx.x;   // over B*T
    if (idx >= BB * TT) return;
    const float* s = x + (size_t)idx * NIN;
    unsigned int w[NIN];
#pragma unroll
    for (int e = 0; e < NIN; ++e) {
        float v = s[e];
        unsigned short hi = bf_rne(v);
        unsigned short lo = bf_rne(v - bf_f32(hi));
        w[e] = (unsigned int)hi | ((unsigned int)lo << 16);
    }
    unsigned int* d = xp + (size_t)idx * 8;
    *(u32x4*)d = (u32x4){w[0], w[1], w[2], w[3]};
    d[4] = w[4];
}

template <bool PACKED>
__global__ __launch_bounds__(512, 4) void lstm_mfma8(
    const float* __restrict__ x,           // [B, T, 5] (fallback path)
    const unsigned int* __restrict__ xpk,  // [B, T, 8] packed (PACKED path)
    const float* __restrict__ W_ih,        // [128, 5]
    const float* __restrict__ W_hh,        // [128, 32]
    const float* __restrict__ b_ih,        // [128]
    const float* __restrict__ b_hh,        // [128]
    const float* __restrict__ W_fc,        // [1, 32]
    const float* __restrict__ b_fc,        // [1]
    float* __restrict__ out)               // [B]
{
    const int tid  = threadIdx.x;
    const int lane = tid & 63;
    const int w    = tid >> 6;   // 0..7
    const int jh   = w & 1;      // j half
    const int rq   = w >> 1;     // acc row quarter 0..3
    const int col  = lane & 15;
    const int kg   = lane >> 4;
    const int b0   = blockIdx.x * 16;

    __shared__ __align__(16) unsigned char hb[2][2048];  // h double buffer (swizzled)

    {   // zero both buffers
        unsigned int* p = (unsigned int*)hb;
        p[tid] = 0u;
        p[tid + 512] = 0u;
    }

    // ---- B fragments (registers, once) ----
    short8 bhi[4], blo[4], b1[4];
#pragma unroll
    for (int t4 = 0; t4 < 4; ++t4) {
        const int r = t4 * 32 + jh * 16 + col;
#pragma unroll
        for (int e = 0; e < 8; ++e) {
            float wv = W_hh[r * HH + kg * 8 + e];
            unsigned short hh = bf_rne(wv);
            bhi[t4][e] = (short)hh;
            blo[t4][e] = (short)bf_rne(wv - bf_f32(hh));
        }
        float bias = b_ih[r] + b_hh[r];
        unsigned short bh = bf_rne(bias);
        unsigned short bl = bf_rne(bias - bf_f32(bh));
        short8 v;
#pragma unroll
        for (int e = 0; e < 8; ++e) v[e] = 0;
        if (kg == 0 || kg == 1) {
#pragma unroll
            for (int e = 0; e < NIN; ++e) v[e] = (short)bf_rne(W_ih[r * NIN + e]);
            v[5] = (short)((kg == 0) ? bh : bl);
        } else if (kg == 2) {
#pragma unroll
            for (int e = 0; e < NIN; ++e) {
                float wv = W_ih[r * NIN + e];
                unsigned short h2 = bf_rne(wv);
                v[e] = (short)bf_rne(wv - bf_f32(h2));
            }
        }
        b1[t4] = v;
    }

    __syncthreads();  // zeros + everything visible

    // ---- per-lane constants ----
    const unsigned shiftv = (kg == 1) ? 16u : 0u;
    const unsigned maskv  = (kg == 3) ? 0u : 0xFFFFu;
    const unsigned b5hi   = (kg < 2) ? (0x3F80u << 16) : 0u;  // 1.0 in a1 slot 5

    const int m = kg * 4 + rq;        // this lane's batch row
    const int j = jh * 16 + col;      // this lane's hidden index
    const unsigned wroff = (unsigned)(m * 128) + (((unsigned)(j * 2)) ^ (((unsigned)(m & 7)) << 4));
    const unsigned rdoff = (unsigned)(col * 128) + (((unsigned)(kg * 16)) ^ (((unsigned)(col & 7)) << 4));

    const int bcol = b0 + col;
    const unsigned int* xq = xpk + (size_t)bcol * TT * 8;
    const float* xf = x + (size_t)bcol * (TT * NIN);

    // current-step x registers
    unsigned int wx[NIN];
    float xsc[NIN];
    if (PACKED) {
        u32x4 q = *(const u32x4*)xq;
        wx[0] = q[0]; wx[1] = q[1]; wx[2] = q[2]; wx[3] = q[3]; wx[4] = xq[4];
    } else {
#pragma unroll
        for (int e = 0; e < NIN; ++e) xsc[e] = xf[e];
    }

    float c = 0.f, hreg = 0.f;
    const f32x4 z = {0.f, 0.f, 0.f, 0.f};

    auto step = [&](int t, int cur) {
        const int nxt = cur ^ 1;

        // prefetch next x (spans the barrier; no vmcnt drain there)
        const int tn = (t + 1 < TT) ? (t + 1) : t;
        unsigned int nwx[NIN];
        float nxs[NIN];
        if (PACKED) {
            const unsigned int* p = xq + (size_t)tn * 8;
            u32x4 q = *(const u32x4*)p;
            nwx[0] = q[0]; nwx[1] = q[1]; nwx[2] = q[2]; nwx[3] = q[3]; nwx[4] = p[4];
        } else {
#pragma unroll
            for (int e = 0; e < NIN; ++e) nxs[e] = xf[tn * NIN + e];
        }

        // A0: h fragment from LDS
        short8 a0 = *(const short8*)&hb[cur][rdoff];

        // A1: x/bias fragment
        short8 a1;
        if (PACKED) {
            unsigned h0 = (wx[0] >> shiftv) & maskv;
            unsigned h1 = (wx[1] >> shiftv) & maskv;
            unsigned h2 = (wx[2] >> shiftv) & maskv;
            unsigned h3 = (wx[3] >> shiftv) & maskv;
            unsigned h4 = (wx[4] >> shiftv) & maskv;
            u32x4 uu = {h0 | (h1 << 16), h2 | (h3 << 16), h4 | b5hi, 0u};
            a1 = __builtin_bit_cast(short8, uu);
        } else {
            unsigned short xh[NIN], xl[NIN];
#pragma unroll
            for (int e = 0; e < NIN; ++e) {
                unsigned short h = bf_rne(xsc[e]);
                xh[e] = h;
                xl[e] = bf_rne(xsc[e] - bf_f32(h));
            }
#pragma unroll
            for (int e = 0; e < NIN; ++e) {
                unsigned short s = (kg == 1) ? xl[e] : xh[e];
                a1[e] = (kg == 3) ? (short)0 : (short)s;
            }
            a1[5] = (kg < 2) ? (short)0x3F80 : (short)0;
            a1[6] = 0; a1[7] = 0;
        }

        // 12 MFMAs: gate t4 = mfma(a1,b1, mfma(a0,bhi, mfma(a0,blo, 0)))
        f32x4 ai = __builtin_amdgcn_mfma_f32_16x16x32_bf16(a0, blo[0], z, 0, 0, 0);
        ai = __builtin_amdgcn_mfma_f32_16x16x32_bf16(a0, bhi[0], ai, 0, 0, 0);
        ai = __builtin_amdgcn_mfma_f32_16x16x32_bf16(a1, b1[0],  ai, 0, 0, 0);
        f32x4 af = __builtin_amdgcn_mfma_f32_16x16x32_bf16(a0, blo[1], z, 0, 0, 0);
        af = __builtin_amdgcn_mfma_f32_16x16x32_bf16(a0, bhi[1], af, 0, 0, 0);
        af = __builtin_amdgcn_mfma_f32_16x16x32_bf16(a1, b1[1],  af, 0, 0, 0);
        f32x4 ag = __builtin_amdgcn_mfma_f32_16x16x32_bf16(a0, blo[2], z, 0, 0, 0);
        ag = __builtin_amdgcn_mfma_f32_16x16x32_bf16(a0, bhi[2], ag, 0, 0, 0);
        ag = __builtin_amdgcn_mfma_f32_16x16x32_bf16(a1, b1[2],  ag, 0, 0, 0);
        f32x4 ao = __builtin_amdgcn_mfma_f32_16x16x32_bf16(a0, blo[3], z, 0, 0, 0);
        ao = __builtin_amdgcn_mfma_f32_16x16x32_bf16(a0, bhi[3], ao, 0, 0, 0);
        ao = __builtin_amdgcn_mfma_f32_16x16x32_bf16(a1, b1[3],  ao, 0, 0, 0);

        // 1 cell/lane: pick acc row rq (wave-uniform -> scalar branch)
        float gi, gf, gg, go;
        switch (rq) {
            case 0:  gi = ai[0]; gf = af[0]; gg = ag[0]; go = ao[0]; break;
            case 1:  gi = ai[1]; gf = af[1]; gg = ag[1]; go = ao[1]; break;
            case 2:  gi = ai[2]; gf = af[2]; gg = ag[2]; go = ao[2]; break;
            default: gi = ai[3]; gf = af[3]; gg = ag[3]; go = ao[3]; break;
        }
        float iv = fast_sigmoid(gi);
        float fv = fast_sigmoid(gf);
        float gv = fast_tanh(gg);
        float ov = fast_sigmoid(go);
        c = fv * c + iv * gv;
        hreg = ov * fast_tanh(c);
        *(unsigned short*)&hb[nxt][wroff] = bf_rne(hreg);

        if (PACKED) {
#pragma unroll
            for (int e = 0; e < NIN; ++e) wx[e] = nwx[e];
        } else {
#pragma unroll
            for (int e = 0; e < NIN; ++e) xsc[e] = nxs[e];
        }

        // h(t+1) visible; keep vmcnt (x prefetch) outstanding across the barrier
        asm volatile("s_waitcnt lgkmcnt(0)" ::: "memory");
        __builtin_amdgcn_s_barrier();
    };

#pragma unroll 1
    for (int t = 0; t < TT; t += 2) {
        step(t, 0);
        step(t + 1, 1);
    }

    // ---- head: out[b] = sum_j h[b][j]*W_fc[j] + b_fc ----
    float* sc = (float*)hb;              // reuse LDS: [16][32] f32
    sc[m * 32 + j] = hreg * W_fc[j];
    __syncthreads();
    if (tid < 16) {
        float s = b_fc[0];
#pragma unroll
        for (int q = 0; q < HH; ++q) s += sc[tid * 32 + q];
        out[b0 + tid] = s;
    }
}

extern "C" void kernel_launch(void* const* d_in, const int* in_sizes, int n_in,
                              void* d_out, int out_size, void* d_ws, size_t ws_size,
                              hipStream_t stream) {
    const float* x    = (const float*)d_in[0];
    const float* W_ih = (const float*)d_in[1];
    const float* W_hh = (const float*)d_in[2];
    const float* b_ih = (const float*)d_in[3];
    const float* b_hh = (const float*)d_in[4];
    const float* W_fc = (const float*)d_in[5];
    const float* b_fc = (const float*)d_in[6];
    float* out = (float*)d_out;

    const size_t need = (size_t)BB * TT * 8 * sizeof(unsigned int);  // 134 MB
    if (ws_size >= need) {
        unsigned int* xp = (unsigned int*)d_ws;
        pack_x<<<dim3((BB * TT + 255) / 256), dim3(256), 0, stream>>>(x, xp);
        lstm_mfma8<true><<<dim3(BB / 16), dim3(512), 0, stream>>>(
            x, xp, W_ih, W_hh, b_ih, b_hh, W_fc, b_fc, out);
    } else {
        lstm_mfma8<false><<<dim3(BB / 16), dim3(512), 0, stream>>>(
            x, nullptr, W_ih, W_hh, b_ih, b_hh, W_fc, b_fc, out);
    }
}

// Round 5
// 330.199 us; speedup vs baseline: 1.5235x; 1.5235x over previous
//
#include <hip/hip_runtime.h>

// LSTM, round 4b: fully in-wave recurrence. B=8192, T=512, IN=5, H=32.
// One wave = 8 batches, 1024 waves = 1 wave/SIMD. No LDS, no barriers.
// gates_T[128 x 8batch] = Wext * hext^T via 8 gate-tiles x 3 MFMAs (Whh_hi,
// Whh_lo, Wx/bias). D-layout puts i,f,g,o for a (j,batch) cell in ONE lane
// (4 cells/lane); next-step B-frag (h^T) rebuilt with 4 __shfl. x split
// hi/lo wave-parallel (1 value/lane) + 5 __shfl broadcast.

typedef __attribute__((ext_vector_type(8))) short short8;
typedef __attribute__((ext_vector_type(4))) float f32x4;
typedef __attribute__((ext_vector_type(4))) unsigned int u32x4;

static constexpr int BB  = 8192;
static constexpr int TT  = 512;
static constexpr int NIN = 5;
static constexpr int HH  = 32;

__device__ __forceinline__ unsigned short bf_rne(float f) {
    unsigned int u = __float_as_uint(f);
    u = (u + 0x7FFFu + ((u >> 16) & 1u)) >> 16;
    return (unsigned short)u;
}
__device__ __forceinline__ float bf_f32(unsigned short h) {
    return __uint_as_float((unsigned int)h << 16);
}
__device__ __forceinline__ float fast_sigmoid(float x) {
    float e = __builtin_amdgcn_exp2f(-1.4426950408889634f * x);
    return __builtin_amdgcn_rcpf(1.0f + e);
}
__device__ __forceinline__ float fast_tanh(float x) {
    float e = __builtin_amdgcn_exp2f(2.8853900817779268f * x);
    return 1.0f - 2.0f * __builtin_amdgcn_rcpf(1.0f + e);
}

__global__ __launch_bounds__(64) void lstm_wave(
    const float* __restrict__ x,     // [B, T, 5]
    const float* __restrict__ W_ih,  // [128, 5]
    const float* __restrict__ W_hh,  // [128, 32]
    const float* __restrict__ b_ih,  // [128]
    const float* __restrict__ b_hh,  // [128]
    const float* __restrict__ W_fc,  // [1, 32]
    const float* __restrict__ b_fc,  // [1]
    float* __restrict__ out)         // [B]
{
    const int lane = threadIdx.x & 63;
    const int col  = lane & 15;      // MFMA col: batch (dup x2) / A-row within tile
    const int kg   = lane >> 4;      // k-group
    const int b0   = blockIdx.x * 8;
    const int bloc = col & 7;        // local batch 0..7
    const bool jlow = (col < 8);     // this lane's cells: j in [jbase, jbase+4)
    const int jbase = 4 * kg + (jlow ? 0 : 16);

    // ---- A-fragments (loop-invariant, registers) ----
    // Tile t4 covers gate rows [16*t4, 16*t4+16); lane holds row gr=16*t4+col,
    // k-slice kg*8+e.  K-tile0 = h (Whh hi/lo).  K-tile1 (x): kg0={Wih_hi,bias_hi},
    // kg1={Wih_hi,bias_lo}, kg2={Wih_lo}, kg3=0.
    short8 Ahh_hi[8], Ahh_lo[8], Ax[8];
#pragma unroll
    for (int t4 = 0; t4 < 8; ++t4) {
        const int gr = 16 * t4 + col;
#pragma unroll
        for (int e = 0; e < 8; ++e) {
            float wv = W_hh[gr * HH + kg * 8 + e];
            unsigned short hi = bf_rne(wv);
            Ahh_hi[t4][e] = (short)hi;
            Ahh_lo[t4][e] = (short)bf_rne(wv - bf_f32(hi));
        }
        float bias = b_ih[gr] + b_hh[gr];
        unsigned short bh_ = bf_rne(bias);
        unsigned short bl_ = bf_rne(bias - bf_f32(bh_));
        short8 v;
#pragma unroll
        for (int e = 0; e < 8; ++e) v[e] = 0;
        if (kg == 0 || kg == 1) {
#pragma unroll
            for (int e = 0; e < NIN; ++e) v[e] = (short)bf_rne(W_ih[gr * NIN + e]);
            v[5] = (short)((kg == 0) ? bh_ : bl_);
        } else if (kg == 2) {
#pragma unroll
            for (int e = 0; e < NIN; ++e) {
                float wv = W_ih[gr * NIN + e];
                unsigned short h2 = bf_rne(wv);
                v[e] = (short)bf_rne(wv - bf_f32(h2));
            }
        }
        Ax[t4] = v;
    }

    // ---- x loader: lane i<40 owns value (batch=i/5, elem=i%5) ----
    const int xb = (lane / 5 < 8) ? (lane / 5) : 7;
    int xe = lane - 5 * xb; if (xe > 4) xe = 4;
    const float* px = x + ((size_t)(b0 + xb) * TT) * NIN + xe;

    // per-lane constants for bx build
    const unsigned shx  = (kg == 1) ? 16u : 0u;                 // hi vs lo extract
    const unsigned mskx = (kg == 3) ? 0u : 0xFFFFu;
    const unsigned one5 = (kg < 2) ? (0x3F80u << 16) : 0u;      // 1.0 in slot 5 hi16

    // h shfl sources
    const int srcA = 32 * (kg & 1) + bloc + 8 * (kg >> 1);
    const int srcB = srcA + 16;

    float xv = px[0]; px += NIN;                 // x for t=0 (in flight)
    unsigned int xpk = 0;
    {   // convert t=0
        unsigned short hi = bf_rne(xv);
        unsigned short lo = bf_rne(xv - bf_f32(hi));
        xpk = (unsigned int)hi | ((unsigned int)lo << 16);
    }

    unsigned int bh0 = 0, bh1 = 0, bh2 = 0, bh3 = 0;  // h^T B-frag (h=0)
    float c0 = 0.f, c1 = 0.f, c2 = 0.f, c3 = 0.f;
    float h0 = 0.f, h1 = 0.f, h2 = 0.f, h3 = 0.f;

    const f32x4 z = {0.f, 0.f, 0.f, 0.f};

#pragma unroll 1
    for (int t = 0; t < TT; ++t) {
        // (1) prefetch next x (covered by this step's compute)
        float xvn = xv;
        if (t + 1 < TT) { xvn = px[0]; px += NIN; }

        // (2) bx from xpk: broadcast 5 packed values of my batch
        unsigned int p0x = (unsigned)__shfl((int)xpk, 5 * bloc + 0, 64);
        unsigned int p1x = (unsigned)__shfl((int)xpk, 5 * bloc + 1, 64);
        unsigned int p2x = (unsigned)__shfl((int)xpk, 5 * bloc + 2, 64);
        unsigned int p3x = (unsigned)__shfl((int)xpk, 5 * bloc + 3, 64);
        unsigned int p4x = (unsigned)__shfl((int)xpk, 5 * bloc + 4, 64);
        unsigned int a0 = (p0x >> shx) & mskx;
        unsigned int a1 = (p1x >> shx) & mskx;
        unsigned int a2 = (p2x >> shx) & mskx;
        unsigned int a3 = (p3x >> shx) & mskx;
        unsigned int a4 = (p4x >> shx) & mskx;
        u32x4 bxu = {a0 | (a1 << 16), a2 | (a3 << 16), a4 | one5, 0u};
        short8 bx = __builtin_bit_cast(short8, bxu);
        u32x4 bhu = {bh0, bh1, bh2, bh3};
        short8 bh = __builtin_bit_cast(short8, bhu);

        // (3) 24 MFMAs, 8 independent 3-chains
        f32x4 acc[8];
#pragma unroll
        for (int t4 = 0; t4 < 8; ++t4)
            acc[t4] = __builtin_amdgcn_mfma_f32_16x16x32_bf16(Ahh_lo[t4], bh, z, 0, 0, 0);
#pragma unroll
        for (int t4 = 0; t4 < 8; ++t4)
            acc[t4] = __builtin_amdgcn_mfma_f32_16x16x32_bf16(Ahh_hi[t4], bh, acc[t4], 0, 0, 0);
#pragma unroll
        for (int t4 = 0; t4 < 8; ++t4)
            acc[t4] = __builtin_amdgcn_mfma_f32_16x16x32_bf16(Ax[t4], bx, acc[t4], 0, 0, 0);

        // (4) cells: lane owns (j = jbase+r, batch = bloc), all 4 gates in-lane
#pragma unroll
        for (int r = 0; r < 4; ++r) {
            float gi = jlow ? acc[0][r] : acc[1][r];
            float gf = jlow ? acc[2][r] : acc[3][r];
            float gg = jlow ? acc[4][r] : acc[5][r];
            float go = jlow ? acc[6][r] : acc[7][r];
            float iv = fast_sigmoid(gi);
            float fv = fast_sigmoid(gf);
            float gv = fast_tanh(gg);
            float ov = fast_sigmoid(go);
            float cc = (r == 0 ? c0 : r == 1 ? c1 : r == 2 ? c2 : c3);
            cc = fv * cc + iv * gv;
            float hh = ov * fast_tanh(cc);
            if (r == 0) { c0 = cc; h0 = hh; }
            else if (r == 1) { c1 = cc; h1 = hh; }
            else if (r == 2) { c2 = cc; h2 = hh; }
            else { c3 = cc; h3 = hh; }
        }

        // (5) pack h -> bf16 pairs (RNE, manual); rebuild bh for t+1 with 4 shfl
        unsigned int p0 = (unsigned int)bf_rne(h0) | ((unsigned int)bf_rne(h1) << 16);
        unsigned int p1 = (unsigned int)bf_rne(h2) | ((unsigned int)bf_rne(h3) << 16);
        bh0 = (unsigned)__shfl((int)p0, srcA, 64);
        bh1 = (unsigned)__shfl((int)p1, srcA, 64);
        bh2 = (unsigned)__shfl((int)p0, srcB, 64);
        bh3 = (unsigned)__shfl((int)p1, srcB, 64);

        // (6) convert next x
        {
            unsigned short hi = bf_rne(xvn);
            unsigned short lo = bf_rne(xvn - bf_f32(hi));
            xpk = (unsigned int)hi | ((unsigned int)lo << 16);
        }
        xv = xvn;
    }

    // ---- head: out[b] = sum_j h[b][j]*W_fc[j] + b_fc ----
    float v = h0 * W_fc[jbase + 0] + h1 * W_fc[jbase + 1]
            + h2 * W_fc[jbase + 2] + h3 * W_fc[jbase + 3];
    v += __shfl_xor(v, 8);    // combine j-low/j-high (col vs col+8)
    v += __shfl_xor(v, 16);   // combine kg
    v += __shfl_xor(v, 32);
    if (lane < 8) out[b0 + lane] = v + b_fc[0];
}

extern "C" void kernel_launch(void* const* d_in, const int* in_sizes, int n_in,
                              void* d_out, int out_size, void* d_ws, size_t ws_size,
                              hipStream_t stream) {
    const float* x    = (const float*)d_in[0];
    const float* W_ih = (const float*)d_in[1];
    const float* W_hh = (const float*)d_in[2];
    const float* b_ih = (const float*)d_in[3];
    const float* b_hh = (const float*)d_in[4];
    const float* W_fc = (const float*)d_in[5];
    const float* b_fc = (const float*)d_in[6];
    float* out = (float*)d_out;

    lstm_wave<<<dim3(BB / 8), dim3(64), 0, stream>>>(
        x, W_ih, W_hh, b_ih, b_hh, W_fc, b_fc, out);
}